// Round 9
// baseline (304.693 us; speedup 1.0000x reference)
//
#include <hip/hip_runtime.h>
#include <hip/hip_bf16.h>
#include <math.h>

typedef float f4 __attribute__((ext_vector_type(4)));

// Problem constants (seed-0 instance): N=2048, T=512, H=256, E=65536, K=10

// ---------------- Kernel 1: fused mean + proj + normalize ----------------
// Phase 1 (R8 winner, unchanged): block-per-row NT streaming mean, 4-acc ILP,
// ~4.9 TB/s (= measured device read-reduce ceiling, matches RMSNorm 4.89).
// Phase 2 (new): x_agg row is already in LDS -> compute e[n] here. Dot of
// W[j] (1KB) split across thread pairs (j, j+128) by c-half, LDS combine,
// 64-lane butterfly for the norm. Saves a launch + 2MB xagg roundtrip.
__global__ __launch_bounds__(256) void mean_proj_kernel(const float* __restrict__ x,
                                                        const float* __restrict__ W,
                                                        float* __restrict__ e,
                                                        int T) {
    const int n   = blockIdx.x;
    const int tid = threadIdx.x;
    const int v   = tid & 63;   // float4 index within row (H/4 == 64)
    const int tg  = tid >> 6;   // wave id 0..3

    __shared__ f4    red[256];
    __shared__ float xs[256];
    __shared__ float pp[256];
    __shared__ float nrm[2];

    const f4* xr = reinterpret_cast<const f4*>(x + (size_t)n * T * 256);
    f4 a0 = {0.f, 0.f, 0.f, 0.f}, a1 = a0, a2 = a0, a3 = a0;
    for (int t = tg; t < T; t += 16) {
        a0 += __builtin_nontemporal_load(&xr[(t     ) * 64 + v]);
        a1 += __builtin_nontemporal_load(&xr[(t +  4) * 64 + v]);
        a2 += __builtin_nontemporal_load(&xr[(t +  8) * 64 + v]);
        a3 += __builtin_nontemporal_load(&xr[(t + 12) * 64 + v]);
    }
    red[tid] = (a0 + a1) + (a2 + a3);
    __syncthreads();
    if (tid < 64) {
        f4 o = (red[tid] + red[tid + 64]) + (red[tid + 128] + red[tid + 192]);
        o *= (1.0f / (float)T);
        *reinterpret_cast<f4*>(&xs[tid * 4]) = o;
    }
    __syncthreads();

    // proj partial: thread (j = tid&127, half = tid>>7) does c in [128h, 128h+128)
    {
        const int j    = tid & 127;
        const int half = tid >> 7;
        const float* Wr = W + (size_t)j * 256 + half * 128;
        const float* xh = xs + half * 128;
        float acc = 0.f;
        #pragma unroll 8
        for (int c = 0; c < 128; ++c) acc = fmaf(Wr[c], xh[c], acc);
        pp[tid] = acc;
    }
    __syncthreads();
    float accf = 0.f;
    if (tid < 128) {
        accf = pp[tid] + pp[tid + 128];
        float s = accf * accf;
        #pragma unroll
        for (int off = 32; off; off >>= 1) s += __shfl_xor(s, off);
        if ((tid & 63) == 0) nrm[tid >> 6] = s;
    }
    __syncthreads();
    if (tid < 128) {
        float inv = 1.0f / fmaxf(sqrtf(nrm[0] + nrm[1]), 1e-12f);
        e[(size_t)n * 128 + tid] = accf * inv;
    }
}

// ---------------- Kernel 2: sim rows + top-11 extraction + dyn scatter --------
// ROWS=4 rows per block, 256 threads. Phase A: j-outer (streaming, R5 form)
// UNROLLED BY 2 (rows j0, j0+256 share the eL broadcast reads -> LDS issue
// halved; per-thread L1 working set stays 2 lines). c4-outer full-coverage
// tiles thrash L1 — do not reintroduce. Phase B: wave w extracts top-11
// (value desc, index asc), drops rank 0 (self).
#define TK_ROWS 4
__global__ __launch_bounds__(256) void simtopk_kernel(const float* __restrict__ e,
                                                      const float* __restrict__ mix,
                                                      float* __restrict__ out,
                                                      int N /*2048*/, int E /*65536*/) {
    __shared__ float eL[TK_ROWS][128];
    __shared__ float simL[TK_ROWS][2048];

    const int i0  = blockIdx.x * TK_ROWS;
    const int tid = threadIdx.x;
    const int M   = E + N * 10;  // 86016

    {
        int r = tid >> 6;
        int c = tid & 63;
        const float* er = e + (size_t)(i0 + r) * 128;
        eL[r][c]      = er[c];
        eL[r][c + 64] = er[c + 64];
    }
    __syncthreads();

    if (N == 2048) {
        // Phase A: pairs (j0, j0+256), j0 = tid + 512p, p = 0..3
        for (int p = 0; p < 4; ++p) {
            const int j0 = tid + p * 512;
            const f4* ejA = reinterpret_cast<const f4*>(e + (size_t)j0 * 128);
            const f4* ejB = reinterpret_cast<const f4*>(e + (size_t)(j0 + 256) * 128);
            float accA[TK_ROWS] = {0.f, 0.f, 0.f, 0.f};
            float accB[TK_ROWS] = {0.f, 0.f, 0.f, 0.f};
            #pragma unroll 4
            for (int c4 = 0; c4 < 32; ++c4) {
                f4 vA = ejA[c4];
                f4 vB = ejB[c4];
                #pragma unroll
                for (int r = 0; r < TK_ROWS; ++r) {
                    f4 qv = *reinterpret_cast<const f4*>(&eL[r][c4 * 4]);
                    accA[r] = fmaf(vA.x, qv.x, accA[r]);
                    accA[r] = fmaf(vA.y, qv.y, accA[r]);
                    accA[r] = fmaf(vA.z, qv.z, accA[r]);
                    accA[r] = fmaf(vA.w, qv.w, accA[r]);
                    accB[r] = fmaf(vB.x, qv.x, accB[r]);
                    accB[r] = fmaf(vB.y, qv.y, accB[r]);
                    accB[r] = fmaf(vB.z, qv.z, accB[r]);
                    accB[r] = fmaf(vB.w, qv.w, accB[r]);
                }
            }
            #pragma unroll
            for (int r = 0; r < TK_ROWS; ++r) {
                simL[r][j0]       = accA[r];
                simL[r][j0 + 256] = accB[r];
            }
        }
    } else {
        for (int j = tid; j < N; j += 256) {
            const f4* ej = reinterpret_cast<const f4*>(e + (size_t)j * 128);
            float acc[TK_ROWS] = {0.f, 0.f, 0.f, 0.f};
            for (int c4 = 0; c4 < 32; ++c4) {
                f4 vv = ej[c4];
                #pragma unroll
                for (int r = 0; r < TK_ROWS; ++r) {
                    const float* el = &eL[r][c4 * 4];
                    acc[r] = fmaf(vv.x, el[0], acc[r]);
                    acc[r] = fmaf(vv.y, el[1], acc[r]);
                    acc[r] = fmaf(vv.z, el[2], acc[r]);
                    acc[r] = fmaf(vv.w, el[3], acc[r]);
                }
            }
            #pragma unroll
            for (int r = 0; r < TK_ROWS; ++r) simL[r][j] = acc[r];
        }
    }
    __syncthreads();

    // Phase B: wave w owns row i0+w
    const int w    = tid >> 6;
    const int lane = tid & 63;
    const int i    = i0 + w;
    const float alpha = 1.0f / (1.0f + expf(-mix[0]));

    float keepv = 0.f;
    int   keepi = 0;
    for (int round = 0; round < 11; ++round) {
        float bv = -3.0f;
        int   bi = N;  // larger than any real index so ties prefer real
        for (int t = 0; t < 32; ++t) {
            int j = t * 64 + lane;
            float v = simL[w][j];
            if (v > bv || (v == bv && j < bi)) { bv = v; bi = j; }
        }
        #pragma unroll
        for (int off = 32; off; off >>= 1) {
            float ov = __shfl_xor(bv, off);
            int   oi = __shfl_xor(bi, off);
            if (ov > bv || (ov == bv && oi < bi)) { bv = ov; bi = oi; }
        }
        if ((bi & 63) == lane && bi < N) simL[w][bi] = -3.0f;
        if (lane == round) { keepv = bv; keepi = bi; }
    }
    if (lane >= 1 && lane <= 10) {
        int kk  = lane - 1;
        int pos = i * 10 + kk;
        out[(size_t)E + pos]         = (float)i;      // row0: src
        out[(size_t)M + E + pos]     = (float)keepi;  // row1: dst
        out[2 * (size_t)M + E + pos] = keepv * alpha; // attr
    }
}

// ---------------- Kernel 3: fixed edges copy/scale ----------------
__global__ __launch_bounds__(256) void fixed_kernel(const int* __restrict__ ei,
                                                    const float* __restrict__ ea,
                                                    const float* __restrict__ mix,
                                                    float* __restrict__ out,
                                                    int E, int M) {
    const int idx = blockIdx.x * blockDim.x + threadIdx.x;
    if (idx < E) {
        float alpha = 1.0f / (1.0f + expf(-mix[0]));
        out[idx]                 = (float)ei[idx];            // row0 fixed src
        out[(size_t)M + idx]     = (float)ei[E + idx];        // row1 fixed dst
        out[2 * (size_t)M + idx] = ea[idx] * (1.0f - alpha);  // fixed attr
    }
}

extern "C" void kernel_launch(void* const* d_in, const int* in_sizes, int n_in,
                              void* d_out, int out_size, void* d_ws, size_t ws_size,
                              hipStream_t stream) {
    const float* x   = (const float*)d_in[0];
    const int*   ei  = (const int*)d_in[1];
    const float* ea  = (const float*)d_in[2];
    const float* W   = (const float*)d_in[3];
    const float* mix = (const float*)d_in[4];

    const int H  = 256;
    const int E  = in_sizes[2];                       // 65536
    const int M  = out_size / 3;                      // 86016
    const int N  = (M - E) / 10;                      // 2048
    const int T  = (int)((size_t)in_sizes[0] / ((size_t)N * H)); // 512

    float* e   = (float*)d_ws;                        // N*128 floats (1 MB)
    float* out = (float*)d_out;

    mean_proj_kernel<<<N, 256, 0, stream>>>(x, W, e, T);
    simtopk_kernel<<<N / TK_ROWS, 256, 0, stream>>>(e, mix, out, N, E);
    fixed_kernel<<<(E + 255) / 256, 256, 0, stream>>>(ei, ea, mix, out, E, M);
}

// Round 10
// 278.285 us; speedup vs baseline: 1.0949x; 1.0949x over previous
//
#include <hip/hip_runtime.h>
#include <hip/hip_bf16.h>
#include <math.h>

typedef float f4 __attribute__((ext_vector_type(4)));

// Problem constants (seed-0 instance): N=2048, T=512, H=256, E=65536, K=10

// ---------------- Kernel 1: fused mean + proj + normalize ----------------
// (R9 form, unchanged this round.) Phase 1: block-per-row NT streaming mean,
// 4-acc ILP, ~4.9 TB/s. Phase 2: proj+normalize in-block from LDS.
__global__ __launch_bounds__(256) void mean_proj_kernel(const float* __restrict__ x,
                                                        const float* __restrict__ W,
                                                        float* __restrict__ e,
                                                        int T) {
    const int n   = blockIdx.x;
    const int tid = threadIdx.x;
    const int v   = tid & 63;   // float4 index within row (H/4 == 64)
    const int tg  = tid >> 6;   // wave id 0..3

    __shared__ f4    red[256];
    __shared__ float xs[256];
    __shared__ float pp[256];
    __shared__ float nrm[2];

    const f4* xr = reinterpret_cast<const f4*>(x + (size_t)n * T * 256);
    f4 a0 = {0.f, 0.f, 0.f, 0.f}, a1 = a0, a2 = a0, a3 = a0;
    for (int t = tg; t < T; t += 16) {
        a0 += __builtin_nontemporal_load(&xr[(t     ) * 64 + v]);
        a1 += __builtin_nontemporal_load(&xr[(t +  4) * 64 + v]);
        a2 += __builtin_nontemporal_load(&xr[(t +  8) * 64 + v]);
        a3 += __builtin_nontemporal_load(&xr[(t + 12) * 64 + v]);
    }
    red[tid] = (a0 + a1) + (a2 + a3);
    __syncthreads();
    if (tid < 64) {
        f4 o = (red[tid] + red[tid + 64]) + (red[tid + 128] + red[tid + 192]);
        o *= (1.0f / (float)T);
        *reinterpret_cast<f4*>(&xs[tid * 4]) = o;
    }
    __syncthreads();

    // proj partial: thread (j = tid&127, half = tid>>7) does c in [128h, 128h+128)
    {
        const int j    = tid & 127;
        const int half = tid >> 7;
        const float* Wr = W + (size_t)j * 256 + half * 128;
        const float* xh = xs + half * 128;
        float acc = 0.f;
        #pragma unroll 8
        for (int c = 0; c < 128; ++c) acc = fmaf(Wr[c], xh[c], acc);
        pp[tid] = acc;
    }
    __syncthreads();
    float accf = 0.f;
    if (tid < 128) {
        accf = pp[tid] + pp[tid + 128];
        float s = accf * accf;
        #pragma unroll
        for (int off = 32; off; off >>= 1) s += __shfl_xor(s, off);
        if ((tid & 63) == 0) nrm[tid >> 6] = s;
    }
    __syncthreads();
    if (tid < 128) {
        float inv = 1.0f / fmaxf(sqrtf(nrm[0] + nrm[1]), 1e-12f);
        e[(size_t)n * 128 + tid] = accf * inv;
    }
}

// ---------------- Kernel 2: sim rows + top-11 extraction + dyn scatter --------
// ROWS=4 rows per block, 256 threads. Phase A: EXACT R5/R8 form (j outer,
// c4 inner, single row per thread) — R9's unroll-by-2 is the suspected
// regression (8 live accumulators + 2 streams under unroll-4 body).
// Phase B: wave w extracts top-11 (value desc, index asc), drops rank 0.
#define TK_ROWS 4
__global__ __launch_bounds__(256) void simtopk_kernel(const float* __restrict__ e,
                                                      const float* __restrict__ mix,
                                                      float* __restrict__ out,
                                                      int N /*2048*/, int E /*65536*/) {
    __shared__ float eL[TK_ROWS][128];
    __shared__ float simL[TK_ROWS][2048];

    const int i0  = blockIdx.x * TK_ROWS;
    const int tid = threadIdx.x;
    const int M   = E + N * 10;  // 86016

    {
        int r = tid >> 6;
        int c = tid & 63;
        const float* er = e + (size_t)(i0 + r) * 128;
        eL[r][c]      = er[c];
        eL[r][c + 64] = er[c + 64];
    }
    __syncthreads();

    // Phase A: sims for all j, 4 rows at once (j outer, c4 inner)
    for (int j = tid; j < N; j += 256) {
        const f4* ej = reinterpret_cast<const f4*>(e + (size_t)j * 128);
        float acc[TK_ROWS] = {0.f, 0.f, 0.f, 0.f};
        #pragma unroll 4
        for (int c4 = 0; c4 < 32; ++c4) {
            f4 vv = ej[c4];
            #pragma unroll
            for (int r = 0; r < TK_ROWS; ++r) {
                const float* el = &eL[r][c4 * 4];
                acc[r] = fmaf(vv.x, el[0], acc[r]);
                acc[r] = fmaf(vv.y, el[1], acc[r]);
                acc[r] = fmaf(vv.z, el[2], acc[r]);
                acc[r] = fmaf(vv.w, el[3], acc[r]);
            }
        }
        #pragma unroll
        for (int r = 0; r < TK_ROWS; ++r) simL[r][j] = acc[r];
    }
    __syncthreads();

    // Phase B: wave w owns row i0+w
    const int w    = tid >> 6;
    const int lane = tid & 63;
    const int i    = i0 + w;
    const float alpha = 1.0f / (1.0f + expf(-mix[0]));

    float keepv = 0.f;
    int   keepi = 0;
    for (int round = 0; round < 11; ++round) {
        float bv = -3.0f;
        int   bi = N;  // larger than any real index so ties prefer real
        for (int t = 0; t < 32; ++t) {
            int j = t * 64 + lane;
            float v = simL[w][j];
            if (v > bv || (v == bv && j < bi)) { bv = v; bi = j; }
        }
        #pragma unroll
        for (int off = 32; off; off >>= 1) {
            float ov = __shfl_xor(bv, off);
            int   oi = __shfl_xor(bi, off);
            if (ov > bv || (ov == bv && oi < bi)) { bv = ov; bi = oi; }
        }
        if ((bi & 63) == lane && bi < N) simL[w][bi] = -3.0f;
        if (lane == round) { keepv = bv; keepi = bi; }
    }
    if (lane >= 1 && lane <= 10) {
        int kk  = lane - 1;
        int pos = i * 10 + kk;
        out[(size_t)E + pos]         = (float)i;      // row0: src
        out[(size_t)M + E + pos]     = (float)keepi;  // row1: dst
        out[2 * (size_t)M + E + pos] = keepv * alpha; // attr
    }
}

// ---------------- Kernel 3: fixed edges copy/scale ----------------
__global__ __launch_bounds__(256) void fixed_kernel(const int* __restrict__ ei,
                                                    const float* __restrict__ ea,
                                                    const float* __restrict__ mix,
                                                    float* __restrict__ out,
                                                    int E, int M) {
    const int idx = blockIdx.x * blockDim.x + threadIdx.x;
    if (idx < E) {
        float alpha = 1.0f / (1.0f + expf(-mix[0]));
        out[idx]                 = (float)ei[idx];            // row0 fixed src
        out[(size_t)M + idx]     = (float)ei[E + idx];        // row1 fixed dst
        out[2 * (size_t)M + idx] = ea[idx] * (1.0f - alpha);  // fixed attr
    }
}

extern "C" void kernel_launch(void* const* d_in, const int* in_sizes, int n_in,
                              void* d_out, int out_size, void* d_ws, size_t ws_size,
                              hipStream_t stream) {
    const float* x   = (const float*)d_in[0];
    const int*   ei  = (const int*)d_in[1];
    const float* ea  = (const float*)d_in[2];
    const float* W   = (const float*)d_in[3];
    const float* mix = (const float*)d_in[4];

    const int H  = 256;
    const int E  = in_sizes[2];                       // 65536
    const int M  = out_size / 3;                      // 86016
    const int N  = (M - E) / 10;                      // 2048
    const int T  = (int)((size_t)in_sizes[0] / ((size_t)N * H)); // 512

    float* e   = (float*)d_ws;                        // N*128 floats (1 MB)
    float* out = (float*)d_out;

    mean_proj_kernel<<<N, 256, 0, stream>>>(x, W, e, T);
    simtopk_kernel<<<N / TK_ROWS, 256, 0, stream>>>(e, mix, out, N, E);
    fixed_kernel<<<(E + 255) / 256, 256, 0, stream>>>(ei, ea, mix, out, E, M);
}